// Round 1
// baseline (212.871 us; speedup 1.0000x reference)
//
#include <hip/hip_runtime.h>

// LiftSplatShoot dims
#define B_   8
#define N_   6
#define D_   41
#define FH_  8
#define FW_  22
#define C_   64
#define NPRIME (B_*N_*D_*FH_*FW_)   // 346368 = 1353 * 256 exactly
#define NBLK_PTS 1353
#define NX0  200
#define NX1  200
#define G1Q  4                      // g1 quarters of 50
#define NB2  (B_ * NX0 * G1Q)       // 6400 buckets (b, g0, g1/50) -- EXACT tiling of out
#define OUTSZ (B_*C_*NX0*NX1)       // 20,480,000 floats = NB2 * 3200
#define MAXTASKS 16384
#define GATHER_BLOCKS 1024          // exactly one co-resident wave of blocks
#define CLS0 384                    // task size-class thresholds (big first)
#define CLS1 96

// ---------------- numpy-faithful fp32 3x3 inverse (LAPACK sgetrf+sgetri) ----
__device__ void lapack_inv3_f32(const float Ain[9], float Aout[9]) {
    #pragma clang fp contract(off)
    float a[9]; // column-major
    for (int r = 0; r < 3; ++r)
        for (int c = 0; c < 3; ++c)
            a[c*3 + r] = Ain[r*3 + c];
    int ipiv[3];
    for (int j = 0; j < 3; ++j) {
        int p = j;
        float amax = fabsf(a[j*3 + j]);
        for (int i = j + 1; i < 3; ++i) {
            float v = fabsf(a[j*3 + i]);
            if (v > amax) { amax = v; p = i; }
        }
        ipiv[j] = p;
        if (p != j)
            for (int c = 0; c < 3; ++c) { float t = a[c*3+j]; a[c*3+j] = a[c*3+p]; a[c*3+p] = t; }
        float d = 1.0f / a[j*3 + j];
        for (int i = j + 1; i < 3; ++i) a[j*3 + i] = a[j*3 + i] * d;
        for (int jj = j + 1; jj < 3; ++jj) {
            float temp = -a[jj*3 + j];
            for (int ii = j + 1; ii < 3; ++ii)
                a[jj*3 + ii] = a[jj*3 + ii] + a[j*3 + ii] * temp;
        }
    }
    for (int j = 0; j < 3; ++j) {
        float ajj_inv = 1.0f / a[j*3 + j];
        a[j*3 + j] = ajj_inv;
        float AJJ = -ajj_inv;
        for (int jj = 0; jj < j; ++jj) {
            float temp = a[j*3 + jj];
            for (int i = 0; i < jj; ++i)
                a[j*3 + i] = a[j*3 + i] + temp * a[jj*3 + i];
            a[j*3 + jj] = a[j*3 + jj] * a[jj*3 + jj];
        }
        for (int i = 0; i < j; ++i) a[j*3 + i] = a[j*3 + i] * AJJ;
    }
    float work[3];
    for (int j = 2; j >= 0; --j) {
        for (int i = j + 1; i < 3; ++i) { work[i] = a[j*3 + i]; a[j*3 + i] = 0.0f; }
        for (int jj = j + 1; jj < 3; ++jj) {
            float temp = -work[jj];
            for (int i = 0; i < 3; ++i)
                a[j*3 + i] = a[j*3 + i] + temp * a[jj*3 + i];
        }
    }
    for (int j = 2; j >= 0; --j) {
        int p = ipiv[j];
        if (p != j)
            for (int i = 0; i < 3; ++i) { float t = a[j*3+i]; a[j*3+i] = a[p*3+i]; a[p*3+i] = t; }
    }
    for (int r = 0; r < 3; ++r)
        for (int c = 0; c < 3; ++c)
            Aout[r*3 + c] = a[c*3 + r];
}

// prep (threads 0..47) + zero bucket counters.
__global__ void prep_kernel(const float* __restrict__ rots,
                            const float* __restrict__ trans,
                            const float* __restrict__ intrins,
                            const float* __restrict__ post_rots,
                            const float* __restrict__ post_trans,
                            float* __restrict__ mats,
                            int* __restrict__ counts) {
    #pragma clang fp contract(off)
    int t = threadIdx.x;
    for (int i = t; i < NB2; i += 256) counts[i] = 0;
    if (t >= B_ * N_) return;
    float pr[9], ipr[9], K[9], iK[9];
    for (int i = 0; i < 9; ++i) { pr[i] = post_rots[t*9 + i]; K[i] = intrins[t*9 + i]; }
    lapack_inv3_f32(pr, ipr);
    lapack_inv3_f32(K, iK);
    float* m = mats + t * 24;
    for (int i = 0; i < 9; ++i) m[i] = ipr[i];
    for (int i = 0; i < 3; ++i)
        for (int k = 0; k < 3; ++k) {
            float s = rots[t*9 + i*3 + 0] * iK[0*3 + k];
            s = s + rots[t*9 + i*3 + 1] * iK[1*3 + k];
            s = s + rots[t*9 + i*3 + 2] * iK[2*3 + k];
            m[9 + i*3 + k] = s;
        }
    for (int i = 0; i < 3; ++i) {
        m[18 + i] = post_trans[t*3 + i];
        m[21 + i] = trans[t*3 + i];
    }
}

// One thread per point (grid exact): fp32 numpy-faithful geometry ->
// pcode=(bk<<6)|g1r; block-local LDS histogram -> hierarchical flush.
// NOTE: no output zeroing here anymore -- gather is the sole dense writer.
__global__ void __launch_bounds__(256) geom_kernel(
        const float* __restrict__ mats,
        unsigned int* __restrict__ pcode,
        int* __restrict__ counts) {
    #pragma clang fp contract(off)
    __shared__ unsigned int hist[NB2];   // 25.6 KB
    int t = threadIdx.x;
    int p = blockIdx.x * 256 + t;
    for (int i = t; i < NB2; i += 256) hist[i] = 0u;
    __syncthreads();

    int w  = p % FW_;
    int h  = (p / FW_) % FH_;
    int d  = (p / (FW_ * FH_)) % D_;
    int bn = p / (FW_ * FH_ * D_);
    int b  = bn / N_;

    const float* m = mats + bn * 24;

    float xs = (w == FW_ - 1) ? 351.0f : (float)((double)w * (351.0 / 21.0));
    float ys = (h == FH_ - 1) ? 127.0f : (float)((double)h * (127.0 / 7.0));
    float ds = 4.0f + (float)d;

    float px = xs - m[18], py = ys - m[19], pz = ds - m[20];
    float qx = m[0]*px;  qx = qx + m[1]*py;  qx = qx + m[2]*pz;
    float qy = m[3]*px;  qy = qy + m[4]*py;  qy = qy + m[5]*pz;
    float qz = m[6]*px;  qz = qz + m[7]*py;  qz = qz + m[8]*pz;

    float ux = qx * qz, uy = qy * qz, uz = qz;

    float gx = m[9]*ux;   gx = gx + m[10]*uy;  gx = gx + m[11]*uz;  gx = gx + m[21];
    float gy = m[12]*ux;  gy = gy + m[13]*uy;  gy = gy + m[14]*uz;  gy = gy + m[22];
    float gz = m[15]*ux;  gz = gz + m[16]*uy;  gz = gz + m[17]*uz;  gz = gz + m[23];

    float cx = (gx - (-50.0f)) / 0.5f;
    float cy = (gy - (-50.0f)) / 0.5f;
    float cz = (gz - (-10.0f)) / 20.0f;
    int g0 = (int)cx;
    int g1 = (int)cy;
    int g2 = (int)cz;

    bool kept = (g0 >= 0) && (g0 < NX0) && (g1 >= 0) && (g1 < NX1) && (g2 == 0);
    if (kept) {
        int g1q = g1 / 50;
        int g1r = g1 - g1q * 50;
        int bk  = (b * NX0 + g0) * G1Q + g1q;
        pcode[p] = ((unsigned int)bk << 6) | (unsigned int)g1r;
        atomicAdd(&hist[bk], 1u);
    } else {
        pcode[p] = 0xFFFFFFFFu;
    }
    __syncthreads();
    for (int i = t; i < NB2; i += 256) {
        unsigned int hv = hist[i];
        if (hv) atomicAdd(&counts[i], (int)hv);
    }
}

// Single-block: exclusive scan over 6400 counts -> offsets, cursor; emit ONE
// task per bucket (all 6400, including empties), ordered by size class
// (big buckets first, empties last) for grid-stride load balance.
__global__ void scan_kernel(const int* __restrict__ counts,
                            int* __restrict__ offsets,
                            int* __restrict__ cursor,
                            unsigned int* __restrict__ tasks,
                            int* __restrict__ task_count) {
    __shared__ int ts[256];
    __shared__ int s0[256], s1[256], s2[256], s3[256];
    int t = threadIdx.x;
    const int PER = NB2 / 256; // 25
    int base = t * PER;
    int mysum = 0;
    int c0 = 0, c1 = 0, c2 = 0, c3 = 0;
    for (int j = 0; j < PER; ++j) {
        int c = counts[base + j];
        mysum += c;
        if (c >= CLS0) c0++;
        else if (c >= CLS1) c1++;
        else if (c > 0) c2++;
        else c3++;
    }
    ts[t] = mysum; s0[t] = c0; s1[t] = c1; s2[t] = c2; s3[t] = c3;
    __syncthreads();
    for (int off = 1; off < 256; off <<= 1) {
        int v  = (t >= off) ? ts[t - off] : 0;
        int a0 = (t >= off) ? s0[t - off] : 0;
        int a1 = (t >= off) ? s1[t - off] : 0;
        int a2 = (t >= off) ? s2[t - off] : 0;
        int a3 = (t >= off) ? s3[t - off] : 0;
        __syncthreads();
        ts[t] += v; s0[t] += a0; s1[t] += a1; s2[t] += a2; s3[t] += a3;
        __syncthreads();
    }
    int run = (t > 0) ? ts[t - 1] : 0;       // exclusive entry base
    int tot0 = s0[255], tot1 = s1[255], tot2 = s2[255];
    int p0 = ((t > 0) ? s0[t - 1] : 0);
    int p1 = tot0 + ((t > 0) ? s1[t - 1] : 0);
    int p2 = tot0 + tot1 + ((t > 0) ? s2[t - 1] : 0);
    int p3 = tot0 + tot1 + tot2 + ((t > 0) ? s3[t - 1] : 0);
    for (int j = 0; j < PER; ++j) {
        int c = counts[base + j];
        offsets[base + j] = run;
        cursor[base + j]  = run;
        run += c;
        unsigned int bkid = (unsigned int)(base + j);
        if (c >= CLS0)      tasks[p0++] = bkid;
        else if (c >= CLS1) tasks[p1++] = bkid;
        else if (c > 0)     tasks[p2++] = bkid;
        else                tasks[p3++] = bkid;
    }
    if (t == 255) {
        offsets[NB2] = run;
        task_count[0] = NB2;
    }
}

// Compact kept points: block-aggregated reservation (one global atomic per
// block x touched-bucket); cnt[] is reused to hold the global base (25.6 KB).
__global__ void __launch_bounds__(256) place_kernel(
        const unsigned int* __restrict__ pcode,
        int* __restrict__ cursor,
        unsigned int* __restrict__ entries) {
    __shared__ int cnt[NB2];   // 25.6 KB (counts, then global bases)
    int t = threadIdx.x;
    int p = blockIdx.x * 256 + t;
    for (int i = t; i < NB2; i += 256) cnt[i] = 0;
    __syncthreads();
    unsigned int code = pcode[p];
    bool kept = (code != 0xFFFFFFFFu);
    int bk = (int)(code >> 6);
    int lr = 0;
    if (kept) lr = atomicAdd(&cnt[bk], 1);
    __syncthreads();
    for (int i = t; i < NB2; i += 256) {
        int c = cnt[i];
        if (c) cnt[i] = atomicAdd(&cursor[i], c);   // overwrite with global base
    }
    __syncthreads();
    if (kept)
        entries[cnt[bk] + lr] = ((code & 63u) << 19) | (unsigned int)p;
}

// Grid-stride gather over exactly NB2 tasks (one per bucket, uncapped, sole
// writer of its 50x64 output region). Out is NOT pre-zeroed: every task plain-
// stores its full region (float2), zeros included -- no global atomics at all.
#define LDS_STRIDE 51
__global__ void __launch_bounds__(512) gather_kernel(
        const float* __restrict__ x_feats,
        const unsigned int* __restrict__ entries,
        const int* __restrict__ offsets,
        const unsigned int* __restrict__ tasks,
        float* __restrict__ out) {
    __shared__ float acc[C_ * LDS_STRIDE]; // 13056 B
    int t = threadIdx.x, wave = t >> 6, lane = t & 63;

    for (int tid = blockIdx.x; tid < NB2; tid += GATHER_BLOCKS) {
        int bk = (int)tasks[tid];
        int s = offsets[bk];
        int e = offsets[bk + 1];
        int n = e - s;

        int b   = bk / (NX0 * G1Q);
        int rem = bk % (NX0 * G1Q);
        int g0  = rem / G1Q, g1q = rem % G1Q;
        size_t obase = (size_t)b * (C_ * NX0 * NX1) + (size_t)g0 * NX1 + g1q * 50;

        if (n == 0) {
            // empty bucket: dense zero store of the whole region (float2-aligned)
            float2 z2 = make_float2(0.f, 0.f);
            for (int k = t; k < C_ * 25; k += 512) {
                int c = k / 25, r2 = k - c * 25;
                *(float2*)&out[obase + (size_t)c * (NX0 * NX1) + (size_t)(r2 * 2)] = z2;
            }
            continue;
        }

        for (int i = t; i < C_ * LDS_STRIDE; i += 512) acc[i] = 0.0f;
        __syncthreads();

        // full 64-entry sweeps: 8 waves x 8-entry ILP
        int nfull = (n >> 6) << 6;
        for (int sbase = 0; sbase < nfull; sbase += 64) {
            int i0 = s + sbase + wave * 8;
            unsigned int v0 = entries[i0],     v1 = entries[i0 + 1];
            unsigned int v2 = entries[i0 + 2], v3 = entries[i0 + 3];
            unsigned int v4 = entries[i0 + 4], v5 = entries[i0 + 5];
            unsigned int v6 = entries[i0 + 6], v7 = entries[i0 + 7];
            float f0 = x_feats[(size_t)(v0 & 0x7FFFFu) * C_ + lane];
            float f1 = x_feats[(size_t)(v1 & 0x7FFFFu) * C_ + lane];
            float f2 = x_feats[(size_t)(v2 & 0x7FFFFu) * C_ + lane];
            float f3 = x_feats[(size_t)(v3 & 0x7FFFFu) * C_ + lane];
            float f4 = x_feats[(size_t)(v4 & 0x7FFFFu) * C_ + lane];
            float f5 = x_feats[(size_t)(v5 & 0x7FFFFu) * C_ + lane];
            float f6 = x_feats[(size_t)(v6 & 0x7FFFFu) * C_ + lane];
            float f7 = x_feats[(size_t)(v7 & 0x7FFFFu) * C_ + lane];
            int lb = lane * LDS_STRIDE;
            atomicAdd(&acc[lb + (int)(v0 >> 19)], f0);
            atomicAdd(&acc[lb + (int)(v1 >> 19)], f1);
            atomicAdd(&acc[lb + (int)(v2 >> 19)], f2);
            atomicAdd(&acc[lb + (int)(v3 >> 19)], f3);
            atomicAdd(&acc[lb + (int)(v4 >> 19)], f4);
            atomicAdd(&acc[lb + (int)(v5 >> 19)], f5);
            atomicAdd(&acc[lb + (int)(v6 >> 19)], f6);
            atomicAdd(&acc[lb + (int)(v7 >> 19)], f7);
        }
        // tail (< 64 entries): one entry per wave per iteration
        for (int i = nfull + wave; i < n; i += 8) {
            unsigned int v = entries[s + i];
            float f = x_feats[(size_t)(v & 0x7FFFFu) * C_ + lane];
            atomicAdd(&acc[lane * LDS_STRIDE + (int)(v >> 19)], f);
        }
        __syncthreads();

        // dense flush: sole writer -> plain float2 stores of ALL 3200 cells
        for (int k = t; k < C_ * 25; k += 512) {
            int c = k / 25, r2 = k - c * 25;
            float2 v = make_float2(acc[c * LDS_STRIDE + 2 * r2],
                                   acc[c * LDS_STRIDE + 2 * r2 + 1]);
            *(float2*)&out[obase + (size_t)c * (NX0 * NX1) + (size_t)(r2 * 2)] = v;
        }
        __syncthreads();   // protect acc before next task's init
    }
}

extern "C" void kernel_launch(void* const* d_in, const int* in_sizes, int n_in,
                              void* d_out, int out_size, void* d_ws, size_t ws_size,
                              hipStream_t stream) {
    const float* x_feats    = (const float*)d_in[0];
    const float* rots       = (const float*)d_in[1];
    const float* trans      = (const float*)d_in[2];
    const float* intrins    = (const float*)d_in[3];
    const float* post_rots  = (const float*)d_in[4];
    const float* post_trans = (const float*)d_in[5];
    float* out = (float*)d_out;

    // ws layout (~3 MB)
    char* w = (char*)d_ws;
    float*        mats       = (float*)w;         w += 48 * 24 * sizeof(float);
    int*          counts     = (int*)w;           w += NB2 * sizeof(int);
    int*          offsets    = (int*)w;           w += (NB2 + 1) * sizeof(int);
    int*          cursor     = (int*)w;           w += NB2 * sizeof(int);
    int*          task_count = (int*)w;           w += 4 * sizeof(int);
    unsigned int* tasks      = (unsigned int*)w;  w += MAXTASKS * sizeof(unsigned int);
    unsigned int* pcode      = (unsigned int*)w;  w += NPRIME * sizeof(unsigned int);
    unsigned int* entries    = (unsigned int*)w;  w += NPRIME * sizeof(unsigned int);

    prep_kernel<<<1, 256, 0, stream>>>(rots, trans, intrins, post_rots, post_trans,
                                       mats, counts);
    geom_kernel<<<NBLK_PTS, 256, 0, stream>>>(mats, pcode, counts);
    scan_kernel<<<1, 256, 0, stream>>>(counts, offsets, cursor, tasks, task_count);
    place_kernel<<<NBLK_PTS, 256, 0, stream>>>(pcode, cursor, entries);
    gather_kernel<<<GATHER_BLOCKS, 512, 0, stream>>>(x_feats, entries, offsets,
                                                     tasks, out);
}

// Round 2
// 210.658 us; speedup vs baseline: 1.0105x; 1.0105x over previous
//
#include <hip/hip_runtime.h>

// LiftSplatShoot dims
#define B_   8
#define N_   6
#define D_   41
#define FH_  8
#define FW_  22
#define C_   64
#define NPRIME (B_*N_*D_*FH_*FW_)   // 346368 = 1353 * 256 exactly
#define NBLK_PTS 1353
#define PTS_PER_CAM (D_*FH_*FW_)    // 7216
#define NX0  200
#define NX1  200
#define G1H  2                      // g1 halves of 100
#define NB2  (B_ * NX0 * G1H)       // 3200 buckets (b, g0, g1/100) -- EXACT tiling of out
#define OUTSZ (B_*C_*NX0*NX1)       // 20,480,000 floats = NB2 * 6400
#define MAXTASKS 16384
#define GATHER_BLOCKS 1024          // 4 blocks/CU x 256 CU, full wave occupancy
#define CAP  384                    // chunking threshold / chunk size
#define CLS1 64                     // "large sole" class threshold
#define LDS_STRIDE 101              // 64ch x 101 floats (odd stride -> 2-way banks)

// ---------------- numpy-faithful fp32 3x3 inverse (LAPACK sgetrf+sgetri) ----
__device__ void lapack_inv3_f32(const float Ain[9], float Aout[9]) {
    #pragma clang fp contract(off)
    float a[9]; // column-major
    for (int r = 0; r < 3; ++r)
        for (int c = 0; c < 3; ++c)
            a[c*3 + r] = Ain[r*3 + c];
    int ipiv[3];
    for (int j = 0; j < 3; ++j) {
        int p = j;
        float amax = fabsf(a[j*3 + j]);
        for (int i = j + 1; i < 3; ++i) {
            float v = fabsf(a[j*3 + i]);
            if (v > amax) { amax = v; p = i; }
        }
        ipiv[j] = p;
        if (p != j)
            for (int c = 0; c < 3; ++c) { float t = a[c*3+j]; a[c*3+j] = a[c*3+p]; a[c*3+p] = t; }
        float d = 1.0f / a[j*3 + j];
        for (int i = j + 1; i < 3; ++i) a[j*3 + i] = a[j*3 + i] * d;
        for (int jj = j + 1; jj < 3; ++jj) {
            float temp = -a[jj*3 + j];
            for (int ii = j + 1; ii < 3; ++ii)
                a[jj*3 + ii] = a[jj*3 + ii] + a[j*3 + ii] * temp;
        }
    }
    for (int j = 0; j < 3; ++j) {
        float ajj_inv = 1.0f / a[j*3 + j];
        a[j*3 + j] = ajj_inv;
        float AJJ = -ajj_inv;
        for (int jj = 0; jj < j; ++jj) {
            float temp = a[j*3 + jj];
            for (int i = 0; i < jj; ++i)
                a[j*3 + i] = a[j*3 + i] + temp * a[jj*3 + i];
            a[j*3 + jj] = a[j*3 + jj] * a[jj*3 + jj];
        }
        for (int i = 0; i < j; ++i) a[j*3 + i] = a[j*3 + i] * AJJ;
    }
    float work[3];
    for (int j = 2; j >= 0; --j) {
        for (int i = j + 1; i < 3; ++i) { work[i] = a[j*3 + i]; a[j*3 + i] = 0.0f; }
        for (int jj = j + 1; jj < 3; ++jj) {
            float temp = -work[jj];
            for (int i = 0; i < 3; ++i)
                a[j*3 + i] = a[j*3 + i] + temp * a[jj*3 + i];
        }
    }
    for (int j = 2; j >= 0; --j) {
        int p = ipiv[j];
        if (p != j)
            for (int i = 0; i < 3; ++i) { float t = a[j*3+i]; a[j*3+i] = a[p*3+i]; a[p*3+i] = t; }
    }
    for (int r = 0; r < 3; ++r)
        for (int c = 0; c < 3; ++c)
            Aout[r*3 + c] = a[c*3 + r];
}

// Build the 24-float mat pack for camera bn (identical fp sequence to the old
// prep_kernel: ipr[9], combine[9]=rots*inv(K), post_trans[3], trans[3]).
__device__ void build_mats(int bn,
                           const float* __restrict__ rots,
                           const float* __restrict__ trans,
                           const float* __restrict__ intrins,
                           const float* __restrict__ post_rots,
                           const float* __restrict__ post_trans,
                           float* m) {
    #pragma clang fp contract(off)
    float pr[9], ipr[9], K[9], iK[9];
    for (int i = 0; i < 9; ++i) { pr[i] = post_rots[bn*9 + i]; K[i] = intrins[bn*9 + i]; }
    lapack_inv3_f32(pr, ipr);
    lapack_inv3_f32(K, iK);
    for (int i = 0; i < 9; ++i) m[i] = ipr[i];
    for (int i = 0; i < 3; ++i)
        for (int k = 0; k < 3; ++k) {
            float s = rots[bn*9 + i*3 + 0] * iK[0*3 + k];
            s = s + rots[bn*9 + i*3 + 1] * iK[1*3 + k];
            s = s + rots[bn*9 + i*3 + 2] * iK[2*3 + k];
            m[9 + i*3 + k] = s;
        }
    for (int i = 0; i < 3; ++i) {
        m[18 + i] = post_trans[bn*3 + i];
        m[21 + i] = trans[bn*3 + i];
    }
}

// One thread per point (grid exact): per-block camera mats (<=2 cams/block),
// fp32 numpy-faithful geometry -> pcode=(bk<<7)|r; LDS histogram -> flush.
__global__ void __launch_bounds__(256) geom_kernel(
        const float* __restrict__ rots,
        const float* __restrict__ trans,
        const float* __restrict__ intrins,
        const float* __restrict__ post_rots,
        const float* __restrict__ post_trans,
        unsigned int* __restrict__ pcode,
        int* __restrict__ counts) {
    #pragma clang fp contract(off)
    __shared__ unsigned int hist[NB2];   // 12.8 KB
    __shared__ float smats[2][24];
    int t = threadIdx.x;
    int p = blockIdx.x * 256 + t;
    int p0blk = blockIdx.x * 256;
    int bnA = p0blk / PTS_PER_CAM;
    int bnB = (p0blk + 255) / PTS_PER_CAM;
    for (int i = t; i < NB2; i += 256) hist[i] = 0u;
    if (t == 0)  build_mats(bnA, rots, trans, intrins, post_rots, post_trans, smats[0]);
    if (t == 64 && bnB != bnA)
                 build_mats(bnB, rots, trans, intrins, post_rots, post_trans, smats[1]);
    __syncthreads();

    int w  = p % FW_;
    int h  = (p / FW_) % FH_;
    int d  = (p / (FW_ * FH_)) % D_;
    int bn = p / PTS_PER_CAM;
    int b  = bn / N_;

    const float* m = smats[bn - bnA];

    float xs = (w == FW_ - 1) ? 351.0f : (float)((double)w * (351.0 / 21.0));
    float ys = (h == FH_ - 1) ? 127.0f : (float)((double)h * (127.0 / 7.0));
    float ds = 4.0f + (float)d;

    float px = xs - m[18], py = ys - m[19], pz = ds - m[20];
    float qx = m[0]*px;  qx = qx + m[1]*py;  qx = qx + m[2]*pz;
    float qy = m[3]*px;  qy = qy + m[4]*py;  qy = qy + m[5]*pz;
    float qz = m[6]*px;  qz = qz + m[7]*py;  qz = qz + m[8]*pz;

    float ux = qx * qz, uy = qy * qz, uz = qz;

    float gx = m[9]*ux;   gx = gx + m[10]*uy;  gx = gx + m[11]*uz;  gx = gx + m[21];
    float gy = m[12]*ux;  gy = gy + m[13]*uy;  gy = gy + m[14]*uz;  gy = gy + m[22];
    float gz = m[15]*ux;  gz = gz + m[16]*uy;  gz = gz + m[17]*uz;  gz = gz + m[23];

    float cx = (gx - (-50.0f)) / 0.5f;
    float cy = (gy - (-50.0f)) / 0.5f;
    float cz = (gz - (-10.0f)) / 20.0f;
    int g0 = (int)cx;
    int g1 = (int)cy;
    int g2 = (int)cz;

    bool kept = (g0 >= 0) && (g0 < NX0) && (g1 >= 0) && (g1 < NX1) && (g2 == 0);
    if (kept) {
        int g1h = g1 / 100;
        int r   = g1 - g1h * 100;
        int bk  = (b * NX0 + g0) * G1H + g1h;
        pcode[p] = ((unsigned int)bk << 7) | (unsigned int)r;
        atomicAdd(&hist[bk], 1u);
    } else {
        pcode[p] = 0xFFFFFFFFu;
    }
    __syncthreads();
    for (int i = t; i < NB2; i += 256) {
        unsigned int hv = hist[i];
        if (hv) atomicAdd(&counts[i], (int)hv);
    }
}

// Single-block (128 threads): exclusive scan over 3200 counts -> offsets,
// cursor; emit tasks ordered {chunked-big, large-sole, small-sole, empty};
// record chunked buckets in zlist for pre-zeroing by place_kernel.
__global__ void scan_kernel(const int* __restrict__ counts,
                            int* __restrict__ offsets,
                            int* __restrict__ cursor,
                            unsigned int* __restrict__ tasks,
                            int* __restrict__ task_count,
                            int* __restrict__ zlist) {
    __shared__ int ts[128], s0[128], s1[128], s2[128], s3[128], s4[128];
    int t = threadIdx.x;
    const int PER = NB2 / 128; // 25
    int base = t * PER;
    int mysum = 0, c0 = 0, c1 = 0, c2 = 0, c3 = 0, c4 = 0;
    for (int j = 0; j < PER; ++j) {
        int c = counts[base + j];
        mysum += c;
        if (c > CAP)       { c0 += (c + CAP - 1) / CAP; c4++; }
        else if (c >= CLS1) c1++;
        else if (c > 0)     c2++;
        else                c3++;
    }
    ts[t] = mysum; s0[t] = c0; s1[t] = c1; s2[t] = c2; s3[t] = c3; s4[t] = c4;
    __syncthreads();
    for (int off = 1; off < 128; off <<= 1) {
        int v  = (t >= off) ? ts[t - off] : 0;
        int a0 = (t >= off) ? s0[t - off] : 0;
        int a1 = (t >= off) ? s1[t - off] : 0;
        int a2 = (t >= off) ? s2[t - off] : 0;
        int a3 = (t >= off) ? s3[t - off] : 0;
        int a4 = (t >= off) ? s4[t - off] : 0;
        __syncthreads();
        ts[t] += v; s0[t] += a0; s1[t] += a1; s2[t] += a2; s3[t] += a3; s4[t] += a4;
        __syncthreads();
    }
    int run  = (t > 0) ? ts[t - 1] : 0;
    int tot0 = s0[127], tot1 = s1[127], tot2 = s2[127], tot3 = s3[127];
    int p0 = ((t > 0) ? s0[t - 1] : 0);
    int p1 = tot0 + ((t > 0) ? s1[t - 1] : 0);
    int p2 = tot0 + tot1 + ((t > 0) ? s2[t - 1] : 0);
    int p3 = tot0 + tot1 + tot2 + ((t > 0) ? s3[t - 1] : 0);
    int pz = ((t > 0) ? s4[t - 1] : 0);
    for (int j = 0; j < PER; ++j) {
        int bk = base + j;
        int c = counts[bk];
        offsets[bk] = run;
        cursor[bk]  = run;
        run += c;
        if (c > CAP) {
            int nch = (c + CAP - 1) / CAP;
            for (int k = 0; k < nch; ++k)
                tasks[p0++] = ((unsigned int)bk << 12) | (unsigned int)k;
            zlist[pz++] = bk;
        } else if (c >= CLS1) tasks[p1++] = (1u << 31) | ((unsigned int)bk << 12);
        else if (c > 0)       tasks[p2++] = (1u << 31) | ((unsigned int)bk << 12);
        else                  tasks[p3++] = (1u << 31) | ((unsigned int)bk << 12);
    }
    if (t == 127) {
        offsets[NB2] = run;
        task_count[0] = tot0 + tot1 + tot2 + tot3;
        task_count[1] = s4[127];
    }
}

// Compact kept points (block-aggregated reservation) + pre-zero the output
// regions of chunked buckets (so gather's chunk tasks can atomic-add safely).
__global__ void __launch_bounds__(256) place_kernel(
        const unsigned int* __restrict__ pcode,
        int* __restrict__ cursor,
        unsigned int* __restrict__ entries,
        const int* __restrict__ task_count,
        const int* __restrict__ zlist,
        float* __restrict__ out) {
    __shared__ int cnt[NB2];   // 12.8 KB (counts, then global bases)
    int t = threadIdx.x;
    int p = blockIdx.x * 256 + t;
    for (int i = t; i < NB2; i += 256) cnt[i] = 0;
    __syncthreads();
    unsigned int code = pcode[p];
    bool kept = (code != 0xFFFFFFFFu);
    int bk = (int)(code >> 7);
    int lr = 0;
    if (kept) lr = atomicAdd(&cnt[bk], 1);
    __syncthreads();
    for (int i = t; i < NB2; i += 256) {
        int c = cnt[i];
        if (c) cnt[i] = atomicAdd(&cursor[i], c);   // overwrite with global base
    }
    __syncthreads();
    if (kept)
        entries[cnt[bk] + lr] = ((code & 127u) << 19) | (unsigned int)p;

    // pre-zero chunked buckets' regions (few; float4 dense)
    int nz = task_count[1];
    int tot = nz * (C_ * 25);            // float4s
    float4 z4 = make_float4(0.f, 0.f, 0.f, 0.f);
    for (int k = p; k < tot; k += NPRIME) {
        int zi = k / (C_ * 25), rem = k - zi * (C_ * 25);
        int zbk = zlist[zi];
        int b = zbk / (NX0 * G1H);
        int rr = zbk % (NX0 * G1H);
        int g0 = rr >> 1, g1h = rr & 1;
        size_t obase = (size_t)b * (C_ * NX0 * NX1) + (size_t)g0 * NX1 + g1h * 100;
        int c = rem / 25, r4 = rem - c * 25;
        *(float4*)&out[obase + (size_t)c * (NX0 * NX1) + 4 * r4] = z4;
    }
}

// Grid-stride gather: sole tasks (incl. empties) are the SOLE writer of their
// 100x64 region -> dense float4 stores (no global atomics, no pre-zero);
// chunk tasks of big buckets sparse-atomic into pre-zeroed regions.
__global__ void __launch_bounds__(512) gather_kernel(
        const float* __restrict__ x_feats,
        const unsigned int* __restrict__ entries,
        const int* __restrict__ offsets,
        const unsigned int* __restrict__ tasks,
        const int* __restrict__ task_count,
        float* __restrict__ out) {
    __shared__ float acc[C_ * LDS_STRIDE]; // 25856 B -> 4 blocks/CU (full occ)
    int ntask = task_count[0];
    int t = threadIdx.x, wave = t >> 6, lane = t & 63;

    for (int tid = blockIdx.x; tid < ntask; tid += GATHER_BLOCKS) {
        unsigned int task = tasks[tid];
        int sole = (int)(task >> 31);
        int bk   = (int)((task >> 12) & 0xFFFu);
        int ch   = (int)(task & 0xFFFu);
        int s = offsets[bk] + ch * CAP;
        int e = offsets[bk + 1];
        if (!sole && e > s + CAP) e = s + CAP;
        int n = e - s;

        int b   = bk / (NX0 * G1H);
        int rem = bk % (NX0 * G1H);
        int g0  = rem >> 1, g1h = rem & 1;
        size_t obase = (size_t)b * (C_ * NX0 * NX1) + (size_t)g0 * NX1 + g1h * 100;

        if (n == 0) {
            // empty bucket: dense zero store (float4, 400B rows)
            float4 z4 = make_float4(0.f, 0.f, 0.f, 0.f);
            for (int k = t; k < C_ * 25; k += 512) {
                int c = k / 25, r4 = k - c * 25;
                *(float4*)&out[obase + (size_t)c * (NX0 * NX1) + 4 * r4] = z4;
            }
            continue;
        }

        for (int i = t; i < C_ * LDS_STRIDE; i += 512) acc[i] = 0.0f;
        __syncthreads();

        // full 64-entry sweeps: 8 waves x 8-entry ILP
        int nfull = (n >> 6) << 6;
        for (int sbase = 0; sbase < nfull; sbase += 64) {
            int i0 = s + sbase + wave * 8;
            unsigned int v0 = entries[i0],     v1 = entries[i0 + 1];
            unsigned int v2 = entries[i0 + 2], v3 = entries[i0 + 3];
            unsigned int v4 = entries[i0 + 4], v5 = entries[i0 + 5];
            unsigned int v6 = entries[i0 + 6], v7 = entries[i0 + 7];
            float f0 = x_feats[(size_t)(v0 & 0x7FFFFu) * C_ + lane];
            float f1 = x_feats[(size_t)(v1 & 0x7FFFFu) * C_ + lane];
            float f2 = x_feats[(size_t)(v2 & 0x7FFFFu) * C_ + lane];
            float f3 = x_feats[(size_t)(v3 & 0x7FFFFu) * C_ + lane];
            float f4 = x_feats[(size_t)(v4 & 0x7FFFFu) * C_ + lane];
            float f5 = x_feats[(size_t)(v5 & 0x7FFFFu) * C_ + lane];
            float f6 = x_feats[(size_t)(v6 & 0x7FFFFu) * C_ + lane];
            float f7 = x_feats[(size_t)(v7 & 0x7FFFFu) * C_ + lane];
            int lb = lane * LDS_STRIDE;
            atomicAdd(&acc[lb + (int)(v0 >> 19)], f0);
            atomicAdd(&acc[lb + (int)(v1 >> 19)], f1);
            atomicAdd(&acc[lb + (int)(v2 >> 19)], f2);
            atomicAdd(&acc[lb + (int)(v3 >> 19)], f3);
            atomicAdd(&acc[lb + (int)(v4 >> 19)], f4);
            atomicAdd(&acc[lb + (int)(v5 >> 19)], f5);
            atomicAdd(&acc[lb + (int)(v6 >> 19)], f6);
            atomicAdd(&acc[lb + (int)(v7 >> 19)], f7);
        }
        // tail (< 64 entries): one entry per wave per iteration
        for (int i = nfull + wave; i < n; i += 8) {
            unsigned int v = entries[s + i];
            float f = x_feats[(size_t)(v & 0x7FFFFu) * C_ + lane];
            atomicAdd(&acc[lane * LDS_STRIDE + (int)(v >> 19)], f);
        }
        __syncthreads();

        if (sole) {
            // sole writer: dense float4 stores of ALL 6400 cells (zeros incl.)
            for (int k = t; k < C_ * 25; k += 512) {
                int c = k / 25, r4 = k - c * 25;
                int lbase = c * LDS_STRIDE + 4 * r4;
                float4 v = make_float4(acc[lbase], acc[lbase + 1],
                                       acc[lbase + 2], acc[lbase + 3]);
                *(float4*)&out[obase + (size_t)c * (NX0 * NX1) + 4 * r4] = v;
            }
        } else {
            // chunk of a big bucket: sparse atomics into pre-zeroed region
            for (int k = t; k < C_ * 100; k += 512) {
                int c = k / 100, r = k - c * 100;
                float val = acc[c * LDS_STRIDE + r];
                if (val != 0.0f)
                    unsafeAtomicAdd(&out[obase + (size_t)c * (NX0 * NX1) + r], val);
            }
        }
        __syncthreads();   // protect acc before next task's init
    }
}

extern "C" void kernel_launch(void* const* d_in, const int* in_sizes, int n_in,
                              void* d_out, int out_size, void* d_ws, size_t ws_size,
                              hipStream_t stream) {
    const float* x_feats    = (const float*)d_in[0];
    const float* rots       = (const float*)d_in[1];
    const float* trans      = (const float*)d_in[2];
    const float* intrins    = (const float*)d_in[3];
    const float* post_rots  = (const float*)d_in[4];
    const float* post_trans = (const float*)d_in[5];
    float* out = (float*)d_out;

    // ws layout (~3 MB)
    char* w = (char*)d_ws;
    int*          counts     = (int*)w;           w += NB2 * sizeof(int);
    int*          offsets    = (int*)w;           w += (NB2 + 1) * sizeof(int);
    int*          cursor     = (int*)w;           w += NB2 * sizeof(int);
    int*          task_count = (int*)w;           w += 4 * sizeof(int);
    unsigned int* tasks      = (unsigned int*)w;  w += MAXTASKS * sizeof(unsigned int);
    int*          zlist      = (int*)w;           w += NB2 * sizeof(int);
    unsigned int* pcode      = (unsigned int*)w;  w += NPRIME * sizeof(unsigned int);
    unsigned int* entries    = (unsigned int*)w;  w += NPRIME * sizeof(unsigned int);

    hipMemsetAsync(counts, 0, NB2 * sizeof(int), stream);
    geom_kernel<<<NBLK_PTS, 256, 0, stream>>>(rots, trans, intrins, post_rots,
                                              post_trans, pcode, counts);
    scan_kernel<<<1, 128, 0, stream>>>(counts, offsets, cursor, tasks,
                                       task_count, zlist);
    place_kernel<<<NBLK_PTS, 256, 0, stream>>>(pcode, cursor, entries,
                                               task_count, zlist, out);
    gather_kernel<<<GATHER_BLOCKS, 512, 0, stream>>>(x_feats, entries, offsets,
                                                     tasks, task_count, out);
}

// Round 3
// 206.969 us; speedup vs baseline: 1.0285x; 1.0178x over previous
//
#include <hip/hip_runtime.h>

// LiftSplatShoot dims
#define B_   8
#define N_   6
#define D_   41
#define FH_  8
#define FW_  22
#define C_   64
#define NPRIME (B_*N_*D_*FH_*FW_)   // 346368 = 1353 * 256 exactly
#define NBLK_PTS 1353
#define PTS_PER_CAM (D_*FH_*FW_)    // 7216
#define NX0  200
#define NX1  200
#define G1H  2                      // g1 halves of 100
#define NB2  (B_ * NX0 * G1H)       // 3200 buckets (b, g0, g1/100) -- EXACT tiling of out
#define OUTSZ (B_*C_*NX0*NX1)       // 20,480,000 floats = NB2 * 6400
#define MAXTASKS 16384
#define GATHER_BLOCKS 4608          // >= worst-case ntask (3200 + ~900 chunks); 1 task/block
#define CAP  384                    // chunking threshold / chunk size
#define CLS1 64                     // "large sole" class threshold
#define LDS_STRIDE 101              // 64ch x 101 floats (odd stride -> conflict-free)

// ---------------- numpy-faithful fp32 3x3 inverse (LAPACK sgetrf+sgetri) ----
__device__ void lapack_inv3_f32(const float Ain[9], float Aout[9]) {
    #pragma clang fp contract(off)
    float a[9]; // column-major
    for (int r = 0; r < 3; ++r)
        for (int c = 0; c < 3; ++c)
            a[c*3 + r] = Ain[r*3 + c];
    int ipiv[3];
    for (int j = 0; j < 3; ++j) {
        int p = j;
        float amax = fabsf(a[j*3 + j]);
        for (int i = j + 1; i < 3; ++i) {
            float v = fabsf(a[j*3 + i]);
            if (v > amax) { amax = v; p = i; }
        }
        ipiv[j] = p;
        if (p != j)
            for (int c = 0; c < 3; ++c) { float t = a[c*3+j]; a[c*3+j] = a[c*3+p]; a[c*3+p] = t; }
        float d = 1.0f / a[j*3 + j];
        for (int i = j + 1; i < 3; ++i) a[j*3 + i] = a[j*3 + i] * d;
        for (int jj = j + 1; jj < 3; ++jj) {
            float temp = -a[jj*3 + j];
            for (int ii = j + 1; ii < 3; ++ii)
                a[jj*3 + ii] = a[jj*3 + ii] + a[j*3 + ii] * temp;
        }
    }
    for (int j = 0; j < 3; ++j) {
        float ajj_inv = 1.0f / a[j*3 + j];
        a[j*3 + j] = ajj_inv;
        float AJJ = -ajj_inv;
        for (int jj = 0; jj < j; ++jj) {
            float temp = a[j*3 + jj];
            for (int i = 0; i < jj; ++i)
                a[j*3 + i] = a[j*3 + i] + temp * a[jj*3 + i];
            a[j*3 + jj] = a[j*3 + jj] * a[jj*3 + jj];
        }
        for (int i = 0; i < j; ++i) a[j*3 + i] = a[j*3 + i] * AJJ;
    }
    float work[3];
    for (int j = 2; j >= 0; --j) {
        for (int i = j + 1; i < 3; ++i) { work[i] = a[j*3 + i]; a[j*3 + i] = 0.0f; }
        for (int jj = j + 1; jj < 3; ++jj) {
            float temp = -work[jj];
            for (int i = 0; i < 3; ++i)
                a[j*3 + i] = a[j*3 + i] + temp * a[jj*3 + i];
        }
    }
    for (int j = 2; j >= 0; --j) {
        int p = ipiv[j];
        if (p != j)
            for (int i = 0; i < 3; ++i) { float t = a[j*3+i]; a[j*3+i] = a[p*3+i]; a[p*3+i] = t; }
    }
    for (int r = 0; r < 3; ++r)
        for (int c = 0; c < 3; ++c)
            Aout[r*3 + c] = a[c*3 + r];
}

// prep (threads 0..47) + zero bucket counters (replaces memset dispatch).
__global__ void prep_kernel(const float* __restrict__ rots,
                            const float* __restrict__ trans,
                            const float* __restrict__ intrins,
                            const float* __restrict__ post_rots,
                            const float* __restrict__ post_trans,
                            float* __restrict__ mats,
                            int* __restrict__ counts) {
    #pragma clang fp contract(off)
    int t = threadIdx.x;
    for (int i = t; i < NB2; i += 256) counts[i] = 0;
    if (t >= B_ * N_) return;
    float pr[9], ipr[9], K[9], iK[9];
    for (int i = 0; i < 9; ++i) { pr[i] = post_rots[t*9 + i]; K[i] = intrins[t*9 + i]; }
    lapack_inv3_f32(pr, ipr);
    lapack_inv3_f32(K, iK);
    float* m = mats + t * 24;
    for (int i = 0; i < 9; ++i) m[i] = ipr[i];
    for (int i = 0; i < 3; ++i)
        for (int k = 0; k < 3; ++k) {
            float s = rots[t*9 + i*3 + 0] * iK[0*3 + k];
            s = s + rots[t*9 + i*3 + 1] * iK[1*3 + k];
            s = s + rots[t*9 + i*3 + 2] * iK[2*3 + k];
            m[9 + i*3 + k] = s;
        }
    for (int i = 0; i < 3; ++i) {
        m[18 + i] = post_trans[t*3 + i];
        m[21 + i] = trans[t*3 + i];
    }
}

// One thread per point (grid exact): fp32 numpy-faithful geometry ->
// pcode=(bk<<7)|r; block-local LDS histogram -> flush.
__global__ void __launch_bounds__(256) geom_kernel(
        const float* __restrict__ mats,
        unsigned int* __restrict__ pcode,
        int* __restrict__ counts) {
    #pragma clang fp contract(off)
    __shared__ unsigned int hist[NB2];   // 12.8 KB
    int t = threadIdx.x;
    int p = blockIdx.x * 256 + t;
    for (int i = t; i < NB2; i += 256) hist[i] = 0u;
    __syncthreads();

    int w  = p % FW_;
    int h  = (p / FW_) % FH_;
    int d  = (p / (FW_ * FH_)) % D_;
    int bn = p / PTS_PER_CAM;
    int b  = bn / N_;

    const float* m = mats + bn * 24;

    float xs = (w == FW_ - 1) ? 351.0f : (float)((double)w * (351.0 / 21.0));
    float ys = (h == FH_ - 1) ? 127.0f : (float)((double)h * (127.0 / 7.0));
    float ds = 4.0f + (float)d;

    float px = xs - m[18], py = ys - m[19], pz = ds - m[20];
    float qx = m[0]*px;  qx = qx + m[1]*py;  qx = qx + m[2]*pz;
    float qy = m[3]*px;  qy = qy + m[4]*py;  qy = qy + m[5]*pz;
    float qz = m[6]*px;  qz = qz + m[7]*py;  qz = qz + m[8]*pz;

    float ux = qx * qz, uy = qy * qz, uz = qz;

    float gx = m[9]*ux;   gx = gx + m[10]*uy;  gx = gx + m[11]*uz;  gx = gx + m[21];
    float gy = m[12]*ux;  gy = gy + m[13]*uy;  gy = gy + m[14]*uz;  gy = gy + m[22];
    float gz = m[15]*ux;  gz = gz + m[16]*uy;  gz = gz + m[17]*uz;  gz = gz + m[23];

    float cx = (gx - (-50.0f)) / 0.5f;
    float cy = (gy - (-50.0f)) / 0.5f;
    float cz = (gz - (-10.0f)) / 20.0f;
    int g0 = (int)cx;
    int g1 = (int)cy;
    int g2 = (int)cz;

    bool kept = (g0 >= 0) && (g0 < NX0) && (g1 >= 0) && (g1 < NX1) && (g2 == 0);
    if (kept) {
        int g1h = g1 / 100;
        int r   = g1 - g1h * 100;
        int bk  = (b * NX0 + g0) * G1H + g1h;
        pcode[p] = ((unsigned int)bk << 7) | (unsigned int)r;
        atomicAdd(&hist[bk], 1u);
    } else {
        pcode[p] = 0xFFFFFFFFu;
    }
    __syncthreads();
    for (int i = t; i < NB2; i += 256) {
        unsigned int hv = hist[i];
        if (hv) atomicAdd(&counts[i], (int)hv);
    }
}

// Single-block (128 threads): exclusive scan over 3200 counts -> offsets,
// cursor; emit tasks ordered {chunked-big, large-sole, small-sole, empty};
// within each class tasks are bucket-ordered (write locality for in-order
// block dispatch). Record chunked buckets in zlist for pre-zeroing.
__global__ void scan_kernel(const int* __restrict__ counts,
                            int* __restrict__ offsets,
                            int* __restrict__ cursor,
                            unsigned int* __restrict__ tasks,
                            int* __restrict__ task_count,
                            int* __restrict__ zlist) {
    __shared__ int ts[128], s0[128], s1[128], s2[128], s3[128], s4[128];
    int t = threadIdx.x;
    const int PER = NB2 / 128; // 25
    int base = t * PER;
    int mysum = 0, c0 = 0, c1 = 0, c2 = 0, c3 = 0, c4 = 0;
    for (int j = 0; j < PER; ++j) {
        int c = counts[base + j];
        mysum += c;
        if (c > CAP)       { c0 += (c + CAP - 1) / CAP; c4++; }
        else if (c >= CLS1) c1++;
        else if (c > 0)     c2++;
        else                c3++;
    }
    ts[t] = mysum; s0[t] = c0; s1[t] = c1; s2[t] = c2; s3[t] = c3; s4[t] = c4;
    __syncthreads();
    for (int off = 1; off < 128; off <<= 1) {
        int v  = (t >= off) ? ts[t - off] : 0;
        int a0 = (t >= off) ? s0[t - off] : 0;
        int a1 = (t >= off) ? s1[t - off] : 0;
        int a2 = (t >= off) ? s2[t - off] : 0;
        int a3 = (t >= off) ? s3[t - off] : 0;
        int a4 = (t >= off) ? s4[t - off] : 0;
        __syncthreads();
        ts[t] += v; s0[t] += a0; s1[t] += a1; s2[t] += a2; s3[t] += a3; s4[t] += a4;
        __syncthreads();
    }
    int run  = (t > 0) ? ts[t - 1] : 0;
    int tot0 = s0[127], tot1 = s1[127], tot2 = s2[127], tot3 = s3[127];
    int p0 = ((t > 0) ? s0[t - 1] : 0);
    int p1 = tot0 + ((t > 0) ? s1[t - 1] : 0);
    int p2 = tot0 + tot1 + ((t > 0) ? s2[t - 1] : 0);
    int p3 = tot0 + tot1 + tot2 + ((t > 0) ? s3[t - 1] : 0);
    int pz = ((t > 0) ? s4[t - 1] : 0);
    for (int j = 0; j < PER; ++j) {
        int bk = base + j;
        int c = counts[bk];
        offsets[bk] = run;
        cursor[bk]  = run;
        run += c;
        if (c > CAP) {
            int nch = (c + CAP - 1) / CAP;
            for (int k = 0; k < nch; ++k)
                tasks[p0++] = ((unsigned int)bk << 12) | (unsigned int)k;
            zlist[pz++] = bk;
        } else if (c >= CLS1) tasks[p1++] = (1u << 31) | ((unsigned int)bk << 12);
        else if (c > 0)       tasks[p2++] = (1u << 31) | ((unsigned int)bk << 12);
        else                  tasks[p3++] = (1u << 31) | ((unsigned int)bk << 12);
    }
    if (t == 127) {
        offsets[NB2] = run;
        task_count[0] = tot0 + tot1 + tot2 + tot3;
        task_count[1] = s4[127];
    }
}

// Compact kept points (block-aggregated reservation) + pre-zero the output
// regions of chunked buckets (so gather's chunk tasks can atomic-add safely).
__global__ void __launch_bounds__(256) place_kernel(
        const unsigned int* __restrict__ pcode,
        int* __restrict__ cursor,
        unsigned int* __restrict__ entries,
        const int* __restrict__ task_count,
        const int* __restrict__ zlist,
        float* __restrict__ out) {
    __shared__ int cnt[NB2];   // 12.8 KB (counts, then global bases)
    int t = threadIdx.x;
    int p = blockIdx.x * 256 + t;
    for (int i = t; i < NB2; i += 256) cnt[i] = 0;
    __syncthreads();
    unsigned int code = pcode[p];
    bool kept = (code != 0xFFFFFFFFu);
    int bk = (int)(code >> 7);
    int lr = 0;
    if (kept) lr = atomicAdd(&cnt[bk], 1);
    __syncthreads();
    for (int i = t; i < NB2; i += 256) {
        int c = cnt[i];
        if (c) cnt[i] = atomicAdd(&cursor[i], c);   // overwrite with global base
    }
    __syncthreads();
    if (kept)
        entries[cnt[bk] + lr] = ((code & 127u) << 19) | (unsigned int)p;

    // pre-zero chunked buckets' regions (few; float4 dense)
    int nz = task_count[1];
    int tot = nz * (C_ * 25);            // float4s
    float4 z4 = make_float4(0.f, 0.f, 0.f, 0.f);
    for (int k = p; k < tot; k += NPRIME) {
        int zi = k / (C_ * 25), rem = k - zi * (C_ * 25);
        int zbk = zlist[zi];
        int b = zbk / (NX0 * G1H);
        int rr = zbk % (NX0 * G1H);
        int g0 = rr >> 1, g1h = rr & 1;
        size_t obase = (size_t)b * (C_ * NX0 * NX1) + (size_t)g0 * NX1 + g1h * 100;
        int c = rem / 25, r4 = rem - c * 25;
        *(float4*)&out[obase + (size_t)c * (NX0 * NX1) + 4 * r4] = z4;
    }
}

// ONE TASK PER BLOCK (no grid-stride): HW scheduler refills CUs continuously
// (no drain tail) and in-order dispatch of bucket-ordered tasks makes
// concurrent blocks write adjacent output segments (DRAM page locality).
// Sole tasks (incl. empties) dense-store their 100x64 region; chunk tasks of
// big buckets sparse-atomic into pre-zeroed regions.
__global__ void __launch_bounds__(512) gather_kernel(
        const float* __restrict__ x_feats,
        const unsigned int* __restrict__ entries,
        const int* __restrict__ offsets,
        const unsigned int* __restrict__ tasks,
        const int* __restrict__ task_count,
        float* __restrict__ out) {
    __shared__ float acc[C_ * LDS_STRIDE]; // 25856 B -> 4 blocks/CU resident
    int tid = blockIdx.x;
    if (tid >= task_count[0]) return;
    int t = threadIdx.x, wave = t >> 6, lane = t & 63;

    unsigned int task = tasks[tid];
    int sole = (int)(task >> 31);
    int bk   = (int)((task >> 12) & 0xFFFu);
    int ch   = (int)(task & 0xFFFu);
    int s = offsets[bk] + ch * CAP;
    int e = offsets[bk + 1];
    if (!sole && e > s + CAP) e = s + CAP;
    int n = e - s;

    int b   = bk / (NX0 * G1H);
    int rem = bk % (NX0 * G1H);
    int g0  = rem >> 1, g1h = rem & 1;
    size_t obase = (size_t)b * (C_ * NX0 * NX1) + (size_t)g0 * NX1 + g1h * 100;

    if (n == 0) {
        // empty bucket: dense zero store (float4, 400B rows)
        float4 z4 = make_float4(0.f, 0.f, 0.f, 0.f);
        for (int k = t; k < C_ * 25; k += 512) {
            int c = k / 25, r4 = k - c * 25;
            *(float4*)&out[obase + (size_t)c * (NX0 * NX1) + 4 * r4] = z4;
        }
        return;
    }

    for (int i = t; i < C_ * LDS_STRIDE; i += 512) acc[i] = 0.0f;
    __syncthreads();

    // full 64-entry sweeps: 8 waves x 8-entry ILP
    int nfull = (n >> 6) << 6;
    for (int sbase = 0; sbase < nfull; sbase += 64) {
        int i0 = s + sbase + wave * 8;
        unsigned int v0 = entries[i0],     v1 = entries[i0 + 1];
        unsigned int v2 = entries[i0 + 2], v3 = entries[i0 + 3];
        unsigned int v4 = entries[i0 + 4], v5 = entries[i0 + 5];
        unsigned int v6 = entries[i0 + 6], v7 = entries[i0 + 7];
        float f0 = x_feats[(size_t)(v0 & 0x7FFFFu) * C_ + lane];
        float f1 = x_feats[(size_t)(v1 & 0x7FFFFu) * C_ + lane];
        float f2 = x_feats[(size_t)(v2 & 0x7FFFFu) * C_ + lane];
        float f3 = x_feats[(size_t)(v3 & 0x7FFFFu) * C_ + lane];
        float f4 = x_feats[(size_t)(v4 & 0x7FFFFu) * C_ + lane];
        float f5 = x_feats[(size_t)(v5 & 0x7FFFFu) * C_ + lane];
        float f6 = x_feats[(size_t)(v6 & 0x7FFFFu) * C_ + lane];
        float f7 = x_feats[(size_t)(v7 & 0x7FFFFu) * C_ + lane];
        int lb = lane * LDS_STRIDE;
        atomicAdd(&acc[lb + (int)(v0 >> 19)], f0);
        atomicAdd(&acc[lb + (int)(v1 >> 19)], f1);
        atomicAdd(&acc[lb + (int)(v2 >> 19)], f2);
        atomicAdd(&acc[lb + (int)(v3 >> 19)], f3);
        atomicAdd(&acc[lb + (int)(v4 >> 19)], f4);
        atomicAdd(&acc[lb + (int)(v5 >> 19)], f5);
        atomicAdd(&acc[lb + (int)(v6 >> 19)], f6);
        atomicAdd(&acc[lb + (int)(v7 >> 19)], f7);
    }
    // tail (< 64 entries): one entry per wave per iteration
    for (int i = nfull + wave; i < n; i += 8) {
        unsigned int v = entries[s + i];
        float f = x_feats[(size_t)(v & 0x7FFFFu) * C_ + lane];
        atomicAdd(&acc[lane * LDS_STRIDE + (int)(v >> 19)], f);
    }
    __syncthreads();

    if (sole) {
        // sole writer: dense float4 stores of ALL 6400 cells (zeros incl.)
        for (int k = t; k < C_ * 25; k += 512) {
            int c = k / 25, r4 = k - c * 25;
            int lbase = c * LDS_STRIDE + 4 * r4;
            float4 v = make_float4(acc[lbase], acc[lbase + 1],
                                   acc[lbase + 2], acc[lbase + 3]);
            *(float4*)&out[obase + (size_t)c * (NX0 * NX1) + 4 * r4] = v;
        }
    } else {
        // chunk of a big bucket: sparse atomics into pre-zeroed region
        for (int k = t; k < C_ * 100; k += 512) {
            int c = k / 100, r = k - c * 100;
            float val = acc[c * LDS_STRIDE + r];
            if (val != 0.0f)
                unsafeAtomicAdd(&out[obase + (size_t)c * (NX0 * NX1) + r], val);
        }
    }
}

extern "C" void kernel_launch(void* const* d_in, const int* in_sizes, int n_in,
                              void* d_out, int out_size, void* d_ws, size_t ws_size,
                              hipStream_t stream) {
    const float* x_feats    = (const float*)d_in[0];
    const float* rots       = (const float*)d_in[1];
    const float* trans      = (const float*)d_in[2];
    const float* intrins    = (const float*)d_in[3];
    const float* post_rots  = (const float*)d_in[4];
    const float* post_trans = (const float*)d_in[5];
    float* out = (float*)d_out;

    // ws layout (~3 MB)
    char* w = (char*)d_ws;
    float*        mats       = (float*)w;         w += 48 * 24 * sizeof(float);
    int*          counts     = (int*)w;           w += NB2 * sizeof(int);
    int*          offsets    = (int*)w;           w += (NB2 + 1) * sizeof(int);
    int*          cursor     = (int*)w;           w += NB2 * sizeof(int);
    int*          task_count = (int*)w;           w += 4 * sizeof(int);
    unsigned int* tasks      = (unsigned int*)w;  w += MAXTASKS * sizeof(unsigned int);
    int*          zlist      = (int*)w;           w += NB2 * sizeof(int);
    unsigned int* pcode      = (unsigned int*)w;  w += NPRIME * sizeof(unsigned int);
    unsigned int* entries    = (unsigned int*)w;  w += NPRIME * sizeof(unsigned int);

    prep_kernel<<<1, 256, 0, stream>>>(rots, trans, intrins, post_rots, post_trans,
                                       mats, counts);
    geom_kernel<<<NBLK_PTS, 256, 0, stream>>>(mats, pcode, counts);
    scan_kernel<<<1, 128, 0, stream>>>(counts, offsets, cursor, tasks,
                                       task_count, zlist);
    place_kernel<<<NBLK_PTS, 256, 0, stream>>>(pcode, cursor, entries,
                                               task_count, zlist, out);
    gather_kernel<<<GATHER_BLOCKS, 512, 0, stream>>>(x_feats, entries, offsets,
                                                     tasks, task_count, out);
}

// Round 4
// 191.896 us; speedup vs baseline: 1.1093x; 1.0785x over previous
//
#include <hip/hip_runtime.h>

// LiftSplatShoot dims
#define B_   8
#define N_   6
#define D_   41
#define FH_  8
#define FW_  22
#define C_   64
#define NPRIME (B_*N_*D_*FH_*FW_)   // 346368 = 1353 * 256 exactly
#define NBLK_PTS 1353
#define PTS_PER_CAM (D_*FH_*FW_)    // 7216
#define NX0  200
#define NX1  200
#define G1H  2                      // g1 halves of 100
#define NB2  (B_ * NX0 * G1H)       // 3200 buckets (b, g0, g1/100)
#define OUTSZ (B_*C_*NX0*NX1)       // 20,480,000 floats
#define RROWS 16                    // g0 rows per render group (13 groups: 12x16+8)

// ---------------- numpy-faithful fp32 3x3 inverse (LAPACK sgetrf+sgetri) ----
__device__ void lapack_inv3_f32(const float Ain[9], float Aout[9]) {
    #pragma clang fp contract(off)
    float a[9]; // column-major
    for (int r = 0; r < 3; ++r)
        for (int c = 0; c < 3; ++c)
            a[c*3 + r] = Ain[r*3 + c];
    int ipiv[3];
    for (int j = 0; j < 3; ++j) {
        int p = j;
        float amax = fabsf(a[j*3 + j]);
        for (int i = j + 1; i < 3; ++i) {
            float v = fabsf(a[j*3 + i]);
            if (v > amax) { amax = v; p = i; }
        }
        ipiv[j] = p;
        if (p != j)
            for (int c = 0; c < 3; ++c) { float t = a[c*3+j]; a[c*3+j] = a[c*3+p]; a[c*3+p] = t; }
        float d = 1.0f / a[j*3 + j];
        for (int i = j + 1; i < 3; ++i) a[j*3 + i] = a[j*3 + i] * d;
        for (int jj = j + 1; jj < 3; ++jj) {
            float temp = -a[jj*3 + j];
            for (int ii = j + 1; ii < 3; ++ii)
                a[jj*3 + ii] = a[jj*3 + ii] + a[j*3 + ii] * temp;
        }
    }
    for (int j = 0; j < 3; ++j) {
        float ajj_inv = 1.0f / a[j*3 + j];
        a[j*3 + j] = ajj_inv;
        float AJJ = -ajj_inv;
        for (int jj = 0; jj < j; ++jj) {
            float temp = a[j*3 + jj];
            for (int i = 0; i < jj; ++i)
                a[j*3 + i] = a[j*3 + i] + temp * a[jj*3 + i];
            a[j*3 + jj] = a[j*3 + jj] * a[jj*3 + jj];
        }
        for (int i = 0; i < j; ++i) a[j*3 + i] = a[j*3 + i] * AJJ;
    }
    float work[3];
    for (int j = 2; j >= 0; --j) {
        for (int i = j + 1; i < 3; ++i) { work[i] = a[j*3 + i]; a[j*3 + i] = 0.0f; }
        for (int jj = j + 1; jj < 3; ++jj) {
            float temp = -work[jj];
            for (int i = 0; i < 3; ++i)
                a[j*3 + i] = a[j*3 + i] + temp * a[jj*3 + i];
        }
    }
    for (int j = 2; j >= 0; --j) {
        int p = ipiv[j];
        if (p != j)
            for (int i = 0; i < 3; ++i) { float t = a[j*3+i]; a[j*3+i] = a[p*3+i]; a[p*3+i] = t; }
    }
    for (int r = 0; r < 3; ++r)
        for (int c = 0; c < 3; ++c)
            Aout[r*3 + c] = a[c*3 + r];
}

// prep (threads 0..47) + zero bucket counters.
__global__ void prep_kernel(const float* __restrict__ rots,
                            const float* __restrict__ trans,
                            const float* __restrict__ intrins,
                            const float* __restrict__ post_rots,
                            const float* __restrict__ post_trans,
                            float* __restrict__ mats,
                            int* __restrict__ counts) {
    #pragma clang fp contract(off)
    int t = threadIdx.x;
    for (int i = t; i < NB2; i += 256) counts[i] = 0;
    if (t >= B_ * N_) return;
    float pr[9], ipr[9], K[9], iK[9];
    for (int i = 0; i < 9; ++i) { pr[i] = post_rots[t*9 + i]; K[i] = intrins[t*9 + i]; }
    lapack_inv3_f32(pr, ipr);
    lapack_inv3_f32(K, iK);
    float* m = mats + t * 24;
    for (int i = 0; i < 9; ++i) m[i] = ipr[i];
    for (int i = 0; i < 3; ++i)
        for (int k = 0; k < 3; ++k) {
            float s = rots[t*9 + i*3 + 0] * iK[0*3 + k];
            s = s + rots[t*9 + i*3 + 1] * iK[1*3 + k];
            s = s + rots[t*9 + i*3 + 2] * iK[2*3 + k];
            m[9 + i*3 + k] = s;
        }
    for (int i = 0; i < 3; ++i) {
        m[18 + i] = post_trans[t*3 + i];
        m[21 + i] = trans[t*3 + i];
    }
}

// One thread per point (grid exact): fp32 numpy-faithful geometry ->
// pcode=(bk<<7)|r; block-local LDS histogram -> flush.
__global__ void __launch_bounds__(256) geom_kernel(
        const float* __restrict__ mats,
        unsigned int* __restrict__ pcode,
        int* __restrict__ counts) {
    #pragma clang fp contract(off)
    __shared__ unsigned int hist[NB2];   // 12.8 KB
    int t = threadIdx.x;
    int p = blockIdx.x * 256 + t;
    for (int i = t; i < NB2; i += 256) hist[i] = 0u;
    __syncthreads();

    int w  = p % FW_;
    int h  = (p / FW_) % FH_;
    int d  = (p / (FW_ * FH_)) % D_;
    int bn = p / PTS_PER_CAM;
    int b  = bn / N_;

    const float* m = mats + bn * 24;

    float xs = (w == FW_ - 1) ? 351.0f : (float)((double)w * (351.0 / 21.0));
    float ys = (h == FH_ - 1) ? 127.0f : (float)((double)h * (127.0 / 7.0));
    float ds = 4.0f + (float)d;

    float px = xs - m[18], py = ys - m[19], pz = ds - m[20];
    float qx = m[0]*px;  qx = qx + m[1]*py;  qx = qx + m[2]*pz;
    float qy = m[3]*px;  qy = qy + m[4]*py;  qy = qy + m[5]*pz;
    float qz = m[6]*px;  qz = qz + m[7]*py;  qz = qz + m[8]*pz;

    float ux = qx * qz, uy = qy * qz, uz = qz;

    float gx = m[9]*ux;   gx = gx + m[10]*uy;  gx = gx + m[11]*uz;  gx = gx + m[21];
    float gy = m[12]*ux;  gy = gy + m[13]*uy;  gy = gy + m[14]*uz;  gy = gy + m[22];
    float gz = m[15]*ux;  gz = gz + m[16]*uy;  gz = gz + m[17]*uz;  gz = gz + m[23];

    float cx = (gx - (-50.0f)) / 0.5f;
    float cy = (gy - (-50.0f)) / 0.5f;
    float cz = (gz - (-10.0f)) / 20.0f;
    int g0 = (int)cx;
    int g1 = (int)cy;
    int g2 = (int)cz;

    bool kept = (g0 >= 0) && (g0 < NX0) && (g1 >= 0) && (g1 < NX1) && (g2 == 0);
    if (kept) {
        int g1h = g1 / 100;
        int r   = g1 - g1h * 100;
        int bk  = (b * NX0 + g0) * G1H + g1h;
        pcode[p] = ((unsigned int)bk << 7) | (unsigned int)r;
        atomicAdd(&hist[bk], 1u);
    } else {
        pcode[p] = 0xFFFFFFFFu;
    }
    __syncthreads();
    for (int i = t; i < NB2; i += 256) {
        unsigned int hv = hist[i];
        if (hv) atomicAdd(&counts[i], (int)hv);
    }
}

// Single-block (128 threads): pure exclusive scan over 3200 counts ->
// offsets (+total at [NB2]) and cursor. No task emission anymore.
__global__ void scan_kernel(const int* __restrict__ counts,
                            int* __restrict__ offsets,
                            int* __restrict__ cursor) {
    __shared__ int ts[128];
    int t = threadIdx.x;
    const int PER = NB2 / 128; // 25
    int base = t * PER;
    int mysum = 0;
    for (int j = 0; j < PER; ++j) mysum += counts[base + j];
    ts[t] = mysum;
    __syncthreads();
    for (int off = 1; off < 128; off <<= 1) {
        int v = (t >= off) ? ts[t - off] : 0;
        __syncthreads();
        ts[t] += v;
        __syncthreads();
    }
    int run = (t > 0) ? ts[t - 1] : 0;
    for (int j = 0; j < PER; ++j) {
        offsets[base + j] = run;
        cursor[base + j]  = run;
        run += counts[base + j];
    }
    if (t == 127) offsets[NB2] = run;
}

// Compact kept points (block-aggregated reservation). Entry encodes
// (g0&15)<<27 | g1<<19 | p  -- g0&15 is the row-local index inside a
// 16-row render group (all group bases are multiples of 16).
__global__ void __launch_bounds__(256) place_kernel(
        const unsigned int* __restrict__ pcode,
        int* __restrict__ cursor,
        unsigned int* __restrict__ entries) {
    __shared__ int cnt[NB2];   // 12.8 KB (counts, then global bases)
    int t = threadIdx.x;
    int p = blockIdx.x * 256 + t;
    for (int i = t; i < NB2; i += 256) cnt[i] = 0;
    __syncthreads();
    unsigned int code = pcode[p];
    bool kept = (code != 0xFFFFFFFFu);
    int bk = (int)(code >> 7);
    int lr = 0;
    if (kept) lr = atomicAdd(&cnt[bk], 1);
    __syncthreads();
    for (int i = t; i < NB2; i += 256) {
        int c = cnt[i];
        if (c) cnt[i] = atomicAdd(&cursor[i], c);   // overwrite with global base
    }
    __syncthreads();
    if (kept) {
        int r   = (int)(code & 127u);
        int bh  = bk >> 1;
        int g0  = bh % NX0;
        int g1  = (bk & 1) * 100 + r;
        entries[cnt[bk] + lr] = ((unsigned int)(g0 & 15) << 27) |
                                ((unsigned int)g1 << 19) | (unsigned int)p;
    }
}

// RENDER: 256 blocks = (batch b, channel-pair cp). Each block is the SOLE
// writer of two contiguous 160KB channel planes out[b][c0..c0+1][...], swept
// sequentially in 13 groups of 16 g0-rows. Per group: LDS-accumulate the
// group's entries (entry load coalesced; x_feats float2 scatter hits LLC),
// then plain sequential float4 stores. No global atomics, no task list,
// uniform per-block cost (all cp blocks of batch b see the same entries).
__global__ void __launch_bounds__(1024) render_kernel(
        const float* __restrict__ x_feats,
        const unsigned int* __restrict__ entries,
        const int* __restrict__ offsets,
        float* __restrict__ out) {
    __shared__ float acc[2 * RROWS * NX1];   // 25.6 KB: [ch][row][g1]
    const int CHS = RROWS * NX1;             // 3200: channel stride in acc
    int blk = blockIdx.x;
    int b  = blk >> 5;          // batch
    int cp = blk & 31;          // channel pair
    int c0 = cp * 2;
    int t = threadIdx.x;
    size_t pl0 = ((size_t)b * C_ + c0) * (NX0 * NX1);
    size_t pl1 = pl0 + (size_t)(NX0 * NX1);

    for (int g = 0; g < (NX0 + RROWS - 1) / RROWS; ++g) {
        int row0  = g * RROWS;
        int nrows = (NX0 - row0 < RROWS) ? (NX0 - row0) : RROWS;
        int nf    = nrows * NX1;             // floats per channel this group

        // zero acc
        for (int i = t; i < 2 * CHS; i += 1024) acc[i] = 0.0f;
        __syncthreads();

        // accumulate entries of the group's 2*nrows buckets
        int bk0 = b * (NX0 * G1H) + row0 * G1H;
        int s = offsets[bk0];
        int e = offsets[bk0 + nrows * G1H];
        for (int i = s + t; i < e; i += 1024) {
            unsigned int v = entries[i];
            int p  = (int)(v & 0x7FFFFu);
            int g1 = (int)((v >> 19) & 0xFFu);
            int rl = (int)(v >> 27);         // g0 & 15 == row-local
            float2 f = *(const float2*)&x_feats[(size_t)p * C_ + c0];
            int a = rl * NX1 + g1;
            atomicAdd(&acc[a], f.x);
            atomicAdd(&acc[CHS + a], f.y);
        }
        __syncthreads();

        // sequential dense flush: nf floats per channel, float4 stores
        int nf4 = nf >> 2;
        size_t ob = (size_t)row0 * NX1;
        for (int k = t; k < 2 * nf4; k += 1024) {
            int ch = k / nf4, kk = k - ch * nf4;
            float4 v = *(float4*)&acc[ch * CHS + kk * 4];
            *(float4*)&out[(ch ? pl1 : pl0) + ob + (size_t)kk * 4] = v;
        }
        __syncthreads();   // protect acc before next group's zero
    }
}

extern "C" void kernel_launch(void* const* d_in, const int* in_sizes, int n_in,
                              void* d_out, int out_size, void* d_ws, size_t ws_size,
                              hipStream_t stream) {
    const float* x_feats    = (const float*)d_in[0];
    const float* rots       = (const float*)d_in[1];
    const float* trans      = (const float*)d_in[2];
    const float* intrins    = (const float*)d_in[3];
    const float* post_rots  = (const float*)d_in[4];
    const float* post_trans = (const float*)d_in[5];
    float* out = (float*)d_out;

    // ws layout (~2.8 MB)
    char* w = (char*)d_ws;
    float*        mats       = (float*)w;         w += 48 * 24 * sizeof(float);
    int*          counts     = (int*)w;           w += NB2 * sizeof(int);
    int*          offsets    = (int*)w;           w += (NB2 + 1) * sizeof(int);
    int*          cursor     = (int*)w;           w += NB2 * sizeof(int);
    unsigned int* pcode      = (unsigned int*)w;  w += NPRIME * sizeof(unsigned int);
    unsigned int* entries    = (unsigned int*)w;  w += NPRIME * sizeof(unsigned int);

    prep_kernel<<<1, 256, 0, stream>>>(rots, trans, intrins, post_rots, post_trans,
                                       mats, counts);
    geom_kernel<<<NBLK_PTS, 256, 0, stream>>>(mats, pcode, counts);
    scan_kernel<<<1, 128, 0, stream>>>(counts, offsets, cursor);
    place_kernel<<<NBLK_PTS, 256, 0, stream>>>(pcode, cursor, entries);
    render_kernel<<<B_ * 32, 1024, 0, stream>>>(x_feats, entries, offsets, out);
}